// Round 1
// baseline (13.899 us; speedup 1.0000x reference)
//
#include <hip/hip_runtime.h>

// Problem constants (from reference):
//   VOCAB=32000, N_ENT=64, N_FACT=512, D=512, B=128, L=128
// Output [B, L, D] float32. For each (b,l):
//   mask==1 -> entities_encoded[b, clamp(ci - VOCAB)]
//   mask==2 -> facts_encoded[b, clamp(ci - VOCAB - N_ENT)]
//   else    -> word_embedding[ci >= VOCAB ? pad : ci]

constexpr int VOCAB  = 32000;
constexpr int N_ENT  = 64;
constexpr int N_FACT = 512;
constexpr int D      = 512;
constexpr int L      = 128;

constexpr int VEC = 4;            // float4 per thread
constexpr int TPR = D / VEC;      // 128 threads per row
constexpr int BLOCK = 256;        // 2 rows per block

__global__ __launch_bounds__(BLOCK) void caption_embed_kernel(
    const int*    __restrict__ idx,     // [B*L] caption_indices
    const float4* __restrict__ ents,    // [B, N_ENT, D/4]
    const float4* __restrict__ facts,   // [B, N_FACT, D/4]
    const float4* __restrict__ words,   // [VOCAB, D/4]
    const int*    __restrict__ pad_tok, // [1]
    const int*    __restrict__ masks,   // [B*L]
    float4*       __restrict__ out,     // [B*L, D/4]
    int n_rows)
{
    const int tid = blockIdx.x * BLOCK + threadIdx.x;
    const int row = tid / TPR;
    const int col = tid % TPR;
    if (row >= n_rows) return;

    const int b  = row / L;
    const int ci = idx[row];
    const int m  = masks[row];

    const float4* src;
    long src_row;
    if (m == 1) {
        int e = ci - VOCAB;
        if (e < 0 || e >= N_ENT) e = N_ENT - 1;
        src = ents;
        src_row = (long)b * N_ENT + e;
    } else if (m == 2) {
        int f = ci - VOCAB - N_ENT;
        if (f < 0 || f >= N_FACT) f = N_FACT - 1;
        src = facts;
        src_row = (long)b * N_FACT + f;
    } else {
        int w = (ci >= VOCAB) ? pad_tok[0] : ci;
        src = words;
        src_row = w;
    }

    out[(long)row * TPR + col] = src[src_row * TPR + col];
}

extern "C" void kernel_launch(void* const* d_in, const int* in_sizes, int n_in,
                              void* d_out, int out_size, void* d_ws, size_t ws_size,
                              hipStream_t stream) {
    const int*    idx     = (const int*)d_in[0];
    const float4* ents    = (const float4*)d_in[1];
    const float4* facts   = (const float4*)d_in[2];
    const float4* words   = (const float4*)d_in[3];
    const int*    pad_tok = (const int*)d_in[4];
    const int*    masks   = (const int*)d_in[5];
    float4*       out     = (float4*)d_out;

    const int n_rows = in_sizes[0];             // B*L = 16384
    const int total  = n_rows * TPR;            // threads needed
    const int grid   = (total + BLOCK - 1) / BLOCK;

    caption_embed_kernel<<<grid, BLOCK, 0, stream>>>(
        idx, ents, facts, words, pad_tok, masks, out, n_rows);
}